// Round 1
// baseline (5255.742 us; speedup 1.0000x reference)
//
#include <hip/hip_runtime.h>
#include <hip/hip_bf16.h>
#include <math.h>

// ---------------- problem constants ----------------
#define SEQLEN   1024
#define D_MODEL  768
#define D_IN     1536
#define D_STATE  16
#define D_CONV   4
#define DT_RANK  48
#define VOCAB    32000
#define N_LAYERS 2
#define KCAT     (D_IN * D_CONV)   // 6144

// ---------------- embedding gather ----------------
__global__ void embed_gather(const int* __restrict__ ids,
                             const float* __restrict__ emb,
                             float* __restrict__ e) {
    int t = blockIdx.x;
    int id = ids[t];
    const float* src = emb + (size_t)id * D_MODEL;
    float* dst = e + (size_t)t * D_MODEL;
    for (int c = threadIdx.x; c < D_MODEL; c += blockDim.x) dst[c] = src[c];
}

// ---------------- rmsnorm (one block per row) ----------------
__global__ __launch_bounds__(256) void rmsnorm_k(const float* __restrict__ in,
                                                 const float* __restrict__ w,
                                                 float* __restrict__ out,
                                                 int cols) {
    int row = blockIdx.x;
    const float* x = in + (size_t)row * cols;
    float ss = 0.f;
    for (int c = threadIdx.x; c < cols; c += 256) { float v = x[c]; ss += v * v; }
    #pragma unroll
    for (int off = 32; off > 0; off >>= 1) ss += __shfl_down(ss, off);
    __shared__ float red[4];
    int lane = threadIdx.x & 63, wv = threadIdx.x >> 6;
    if (lane == 0) red[wv] = ss;
    __syncthreads();
    float tot = red[0] + red[1] + red[2] + red[3];
    float scale = rsqrtf(tot / (float)cols + 1e-5f);
    for (int c = threadIdx.x; c < cols; c += 256)
        out[(size_t)row * cols + c] = x[c] * scale * w[c];
}

// ---------------- build Xcat for the full causal conv ----------------
// Xcat[t][i*4+k] = x[t-3+k][i]  (zero when t-3+k < 0)
// Then conv == GEMM:  xc[t][o] = sum_j Xcat[t][j] * W_conv[o][j]   (W_conv row o is
// contiguous [i][k] = 6144 floats, exactly matching j = i*4+k).
__global__ void build_xcat(const float* __restrict__ x, float* __restrict__ xc) {
    int idx = blockIdx.x * blockDim.x + threadIdx.x;  // t*D_IN + i
    if (idx >= SEQLEN * D_IN) return;
    int t = idx / D_IN, i = idx - t * D_IN;
    float4 v;
    v.x = (t >= 3) ? x[(size_t)(t - 3) * D_IN + i] : 0.f;
    v.y = (t >= 2) ? x[(size_t)(t - 2) * D_IN + i] : 0.f;
    v.z = (t >= 1) ? x[(size_t)(t - 1) * D_IN + i] : 0.f;
    v.w = x[(size_t)t * D_IN + i];
    *(float4*)(xc + (size_t)idx * 4) = v;
}

// ---------------- generic fp32 GEMM:  C[M,N] = A[M,K] @ W[N,K]^T (+bias)(+act)(+resid)
// act: 0=none, 1=silu, 2=softplus
#define BM 64
#define BN 64
#define BK 16
__global__ __launch_bounds__(256) void gemm_fp32(
    const float* __restrict__ A, const float* __restrict__ W,
    const float* __restrict__ bias, const float* __restrict__ resid,
    float* __restrict__ C, int M, int N, int K, int act) {
    __shared__ float As[BK][BM + 1];
    __shared__ float Ws[BK][BN + 1];
    int tid = threadIdx.x;
    int tx = tid & 15, ty = tid >> 4;           // 16 x 16 thread grid
    int m0 = blockIdx.y * BM, n0 = blockIdx.x * BN;
    float acc[4][4] = {};
    for (int k0 = 0; k0 < K; k0 += BK) {
        int r  = tid >> 2;           // 0..63
        int c4 = (tid & 3) * 4;      // 0,4,8,12
        const float4 av = *(const float4*)(A + (size_t)(m0 + r) * K + k0 + c4);
        As[c4 + 0][r] = av.x; As[c4 + 1][r] = av.y;
        As[c4 + 2][r] = av.z; As[c4 + 3][r] = av.w;
        int n = n0 + r;
        float4 wv = make_float4(0.f, 0.f, 0.f, 0.f);
        if (n < N) wv = *(const float4*)(W + (size_t)n * K + k0 + c4);
        Ws[c4 + 0][r] = wv.x; Ws[c4 + 1][r] = wv.y;
        Ws[c4 + 2][r] = wv.z; Ws[c4 + 3][r] = wv.w;
        __syncthreads();
        #pragma unroll
        for (int k = 0; k < BK; ++k) {
            float a[4], b[4];
            #pragma unroll
            for (int i = 0; i < 4; ++i) a[i] = As[k][ty + 16 * i];
            #pragma unroll
            for (int j = 0; j < 4; ++j) b[j] = Ws[k][tx + 16 * j];
            #pragma unroll
            for (int i = 0; i < 4; ++i)
                #pragma unroll
                for (int j = 0; j < 4; ++j) acc[i][j] += a[i] * b[j];
        }
        __syncthreads();
    }
    #pragma unroll
    for (int i = 0; i < 4; ++i) {
        int m = m0 + ty + 16 * i;
        #pragma unroll
        for (int j = 0; j < 4; ++j) {
            int n = n0 + tx + 16 * j;
            if (n >= N) continue;
            float v = acc[i][j];
            if (bias) v += bias[n];
            if (act == 1)      v = v / (1.f + __expf(-v));                  // silu
            else if (act == 2) v = (v > 20.f) ? v : log1pf(__expf(v));      // softplus
            if (resid) v += resid[(size_t)m * N + n];
            C[(size_t)m * N + n] = v;
        }
    }
}

// ---------------- selective-scan: thread = (channel d, state n) ----------------
// s[t] = exp(delta*A)*s[t-1] + delta*u*B ; y[t,d] = sum_n s*C ; fused epilogue:
// y = (y + u*D) * silu(res)
__global__ __launch_bounds__(256) void scan_k(
    const float* __restrict__ delta, const float* __restrict__ u,
    const float* __restrict__ Bm, const float* __restrict__ Cm,
    const float* __restrict__ A_log, const float* __restrict__ Dp,
    const float* __restrict__ res, float* __restrict__ y) {
    int tid = blockIdx.x * 256 + threadIdx.x;
    int d = tid >> 4, n = tid & 15;
    float A  = -__expf(A_log[d * D_STATE + n]);
    float Dd = Dp[d];
    float s = 0.f;
    for (int t = 0; t < SEQLEN; ++t) {
        float dlt = delta[(size_t)t * D_IN + d];
        float ut  = u[(size_t)t * D_IN + d];
        float Bt  = Bm[t * D_STATE + n];
        float Ct  = Cm[t * D_STATE + n];
        s = __expf(dlt * A) * s + dlt * ut * Bt;
        float p = s * Ct;
        p += __shfl_xor(p, 1);
        p += __shfl_xor(p, 2);
        p += __shfl_xor(p, 4);
        p += __shfl_xor(p, 8);
        if (n == 0) {
            float r = res[(size_t)t * D_IN + d];
            y[(size_t)t * D_IN + d] = (p + ut * Dd) * (r / (1.f + __expf(-r)));
        }
    }
}

// ---------------- host side ----------------
static inline void launch_gemm(const float* A, const float* W, const float* bias,
                               const float* resid, float* C,
                               int M, int N, int K, int act, hipStream_t stream) {
    dim3 grid((N + BN - 1) / BN, (M + BM - 1) / BM);
    gemm_fp32<<<grid, 256, 0, stream>>>(A, W, bias, resid, C, M, N, K, act);
}

extern "C" void kernel_launch(void* const* d_in, const int* in_sizes, int n_in,
                              void* d_out, int out_size, void* d_ws, size_t ws_size,
                              hipStream_t stream) {
    const int*   ids      = (const int*)d_in[0];
    const float* emb      = (const float*)d_in[1];
    const float* W_res    = (const float*)d_in[2];
    const float* b_res    = (const float*)d_in[3];
    const float* W_state  = (const float*)d_in[4];
    const float* b_state  = (const float*)d_in[5];
    const float* W_conv   = (const float*)d_in[6];
    const float* W_dt     = (const float*)d_in[7];
    const float* b_dt     = (const float*)d_in[8];
    const float* W_B      = (const float*)d_in[9];
    const float* b_B      = (const float*)d_in[10];
    const float* W_C      = (const float*)d_in[11];
    const float* b_C      = (const float*)d_in[12];
    const float* W_dtp    = (const float*)d_in[13];
    const float* b_dtp    = (const float*)d_in[14];
    const float* A_log    = (const float*)d_in[15];
    const float* D_param  = (const float*)d_in[16];
    const float* W_out    = (const float*)d_in[17];
    const float* b_out    = (const float*)d_in[18];
    const float* norm_w   = (const float*)d_in[19];
    const float* fnorm_w  = (const float*)d_in[20];
    float* out = (float*)d_out;

    // workspace carve-up (floats)
    float* p = (float*)d_ws;
    float* e     = p; p += SEQLEN * D_MODEL;   // 786432
    float* xn    = p; p += SEQLEN * D_MODEL;   // 786432
    float* resb  = p; p += SEQLEN * D_IN;      // 1572864
    float* x     = p; p += SEQLEN * D_IN;
    float* xcat  = p; p += SEQLEN * KCAT;      // 6291456
    float* u     = p; p += SEQLEN * D_IN;
    float* dtl   = p; p += SEQLEN * DT_RANK;   // 49152
    float* delta = p; p += SEQLEN * D_IN;
    float* Bm    = p; p += SEQLEN * D_STATE;   // 16384
    float* Cm    = p; p += SEQLEN * D_STATE;
    float* y     = p; p += SEQLEN * D_IN;

    embed_gather<<<SEQLEN, 256, 0, stream>>>(ids, emb, e);

    for (int i = 0; i < N_LAYERS; ++i) {
        const float* Wres_i  = W_res   + (size_t)i * D_IN * D_MODEL;
        const float* bres_i  = b_res   + (size_t)i * D_IN;
        const float* Wst_i   = W_state + (size_t)i * D_IN * D_MODEL;
        const float* bst_i   = b_state + (size_t)i * D_IN;
        const float* Wcv_i   = W_conv  + (size_t)i * D_IN * KCAT;
        const float* Wdt_i   = W_dt    + (size_t)i * DT_RANK * D_IN;
        const float* bdt_i   = b_dt    + (size_t)i * DT_RANK;
        const float* WB_i    = W_B     + (size_t)i * D_STATE * D_IN;
        const float* bB_i    = b_B     + (size_t)i * D_STATE;
        const float* WC_i    = W_C     + (size_t)i * D_STATE * D_IN;
        const float* bC_i    = b_C     + (size_t)i * D_STATE;
        const float* Wdtp_i  = W_dtp   + (size_t)i * D_IN * DT_RANK;
        const float* bdtp_i  = b_dtp   + (size_t)i * D_IN;
        const float* Alog_i  = A_log   + (size_t)i * D_IN * D_STATE;
        const float* Dp_i    = D_param + (size_t)i * D_IN;
        const float* Wout_i  = W_out   + (size_t)i * D_MODEL * D_IN;
        const float* bout_i  = b_out   + (size_t)i * D_MODEL;
        const float* nw_i    = norm_w  + (size_t)i * D_MODEL;

        rmsnorm_k<<<SEQLEN, 256, 0, stream>>>(e, nw_i, xn, D_MODEL);
        launch_gemm(xn, Wres_i, bres_i, nullptr, resb, SEQLEN, D_IN, D_MODEL, 0, stream);
        launch_gemm(xn, Wst_i,  bst_i,  nullptr, x,    SEQLEN, D_IN, D_MODEL, 0, stream);
        build_xcat<<<(SEQLEN * D_IN + 255) / 256, 256, 0, stream>>>(x, xcat);
        launch_gemm(xcat, Wcv_i, nullptr, nullptr, u, SEQLEN, D_IN, KCAT, 1, stream);  // +silu
        launch_gemm(u, Wdt_i, bdt_i, nullptr, dtl, SEQLEN, DT_RANK, D_IN, 0, stream);
        launch_gemm(dtl, Wdtp_i, bdtp_i, nullptr, delta, SEQLEN, D_IN, DT_RANK, 2, stream); // softplus
        launch_gemm(u, WB_i, bB_i, nullptr, Bm, SEQLEN, D_STATE, D_IN, 0, stream);
        launch_gemm(u, WC_i, bC_i, nullptr, Cm, SEQLEN, D_STATE, D_IN, 0, stream);
        scan_k<<<(D_IN * D_STATE) / 256, 256, 0, stream>>>(delta, u, Bm, Cm,
                                                           Alog_i, Dp_i, resb, y);
        // e = y @ W_out^T + b_out + e   (in-place residual is safe: each element
        // is read once in the epilogue by the same thread that writes it)
        launch_gemm(y, Wout_i, bout_i, e, e, SEQLEN, D_MODEL, D_IN, 0, stream);
    }

    rmsnorm_k<<<SEQLEN, 256, 0, stream>>>(e, fnorm_w, xn, D_MODEL);
    launch_gemm(xn, emb, nullptr, nullptr, out, SEQLEN, VOCAB, D_MODEL, 0, stream);
}

// Round 3
// 3171.267 us; speedup vs baseline: 1.6573x; 1.6573x over previous
//
#include <hip/hip_runtime.h>
#include <hip/hip_bf16.h>
#include <math.h>
#include <stdint.h>

// ---------------- problem constants ----------------
#define SEQLEN   1024
#define D_MODEL  768
#define D_IN     1536
#define D_STATE  16
#define D_CONV   4
#define DT_RANK  48
#define VOCAB    32000
#define N_LAYERS 2
#define KCAT     (D_IN * D_CONV)   // 6144

using bf16x8 = __attribute__((ext_vector_type(8))) short;
using f32x4  = __attribute__((ext_vector_type(4))) float;

__device__ __forceinline__ unsigned short f2bf(float f) {
    unsigned u = __builtin_bit_cast(unsigned, f);
    unsigned r = u + 0x7FFFu + ((u >> 16) & 1u);   // round-to-nearest-even
    return (unsigned short)(r >> 16);
}

// async global->LDS, 16 bytes per lane. NOTE: address-space conversion needs
// C-style casts (clang addrspacecast); reinterpret_cast is rejected.
__device__ __forceinline__ void gload_lds16(const unsigned short* g, unsigned short* l) {
    auto* lds = (__attribute__((address_space(3))) unsigned int*)(l);
    auto* gp  = (const __attribute__((address_space(1))) unsigned int*)(g);
    __builtin_amdgcn_global_load_lds(gp, lds, 16, 0, 0);
}

// ---------------- fp32 -> bf16 cast (vectorized, 8 elems/thread) ----------------
__global__ __launch_bounds__(256) void cast_f32_bf16(const float* __restrict__ in,
                                                     unsigned short* __restrict__ out, int n) {
    int i = (blockIdx.x * 256 + threadIdx.x) * 8;
    if (i >= n) return;
    float4 a = *(const float4*)(in + i);
    float4 b = *(const float4*)(in + i + 4);
    uint4 v;
    v.x = f2bf(a.x) | ((unsigned)f2bf(a.y) << 16);
    v.y = f2bf(a.z) | ((unsigned)f2bf(a.w) << 16);
    v.z = f2bf(b.x) | ((unsigned)f2bf(b.y) << 16);
    v.w = f2bf(b.z) | ((unsigned)f2bf(b.w) << 16);
    *(uint4*)(out + i) = v;
}

// ---------------- embedding gather (fp32) ----------------
__global__ void embed_gather(const int* __restrict__ ids,
                             const float* __restrict__ emb,
                             float* __restrict__ e) {
    int t = blockIdx.x;
    int id = ids[t];
    const float* src = emb + (size_t)id * D_MODEL;
    float* dst = e + (size_t)t * D_MODEL;
    for (int c = threadIdx.x; c < D_MODEL; c += blockDim.x) dst[c] = src[c];
}

// ---------------- rmsnorm: fp32 in, bf16 out ----------------
__global__ __launch_bounds__(256) void rmsnorm_k(const float* __restrict__ in,
                                                 const float* __restrict__ w,
                                                 unsigned short* __restrict__ out,
                                                 int cols) {
    int row = blockIdx.x;
    const float* x = in + (size_t)row * cols;
    float ss = 0.f;
    for (int c = threadIdx.x; c < cols; c += 256) { float v = x[c]; ss += v * v; }
    #pragma unroll
    for (int off = 32; off > 0; off >>= 1) ss += __shfl_down(ss, off);
    __shared__ float red[4];
    int lane = threadIdx.x & 63, wv = threadIdx.x >> 6;
    if (lane == 0) red[wv] = ss;
    __syncthreads();
    float tot = red[0] + red[1] + red[2] + red[3];
    float scale = rsqrtf(tot / (float)cols + 1e-5f);
    for (int c = threadIdx.x; c < cols; c += 256)
        out[(size_t)row * cols + c] = f2bf(x[c] * scale * w[c]);
}

// ---------------- build Xcat (bf16 out) ----------------
// Xcat[t][i*4+k] = x[t-3+k][i]  (zero when t-3+k < 0)
__global__ void build_xcat(const float* __restrict__ x, unsigned short* __restrict__ xc) {
    int idx = blockIdx.x * blockDim.x + threadIdx.x;  // t*D_IN + i
    if (idx >= SEQLEN * D_IN) return;
    int t = idx / D_IN, i = idx - t * D_IN;
    unsigned short h0 = (t >= 3) ? f2bf(x[(size_t)(t - 3) * D_IN + i]) : 0;
    unsigned short h1 = (t >= 2) ? f2bf(x[(size_t)(t - 2) * D_IN + i]) : 0;
    unsigned short h2 = (t >= 1) ? f2bf(x[(size_t)(t - 1) * D_IN + i]) : 0;
    unsigned short h3 = f2bf(x[(size_t)t * D_IN + i]);
    uint2 v;
    v.x = h0 | ((unsigned)h1 << 16);
    v.y = h2 | ((unsigned)h3 << 16);
    *(uint2*)(xc + (size_t)idx * 4) = v;
}

// ---------------- bf16 MFMA GEMM:  C[M,N] = A[M,K] @ B[N,K]^T (+bias)(+act)(+resid)
// 128x128 tile, 4 waves (2x2), each wave 64x64 = 4x4 frags of 16x16, BK=32.
// Requires: M%128==0, N%128==0, K%32==0. act: 0=none, 1=silu
__global__ __launch_bounds__(256) void gemm_bf16(
    const unsigned short* __restrict__ A, const unsigned short* __restrict__ B,
    const float* __restrict__ bias, const float* __restrict__ resid,
    float* __restrict__ C, int M, int N, int K, int act) {
    __shared__ unsigned short As[128 * 32];
    __shared__ unsigned short Bs[128 * 32];
    const int tid = threadIdx.x;
    const int wid = tid >> 6, lane = tid & 63;
    const int wr = wid >> 1, wc = wid & 1;
    const int m0 = blockIdx.y * 128, n0 = blockIdx.x * 128;

    f32x4 acc[4][4] = {};

    // staging: 2 rounds x 16B per thread per operand; LDS linear [row][k], row=idx/32
    const int si0 = tid * 8;                       // element index, round 0
    const int si1 = (tid + 256) * 8;               // round 1
    const int row0 = si0 >> 5, ke0 = si0 & 31;
    const int row1 = si1 >> 5, ke1 = si1 & 31;
    const unsigned short* Ag0 = A + (size_t)(m0 + row0) * K + ke0;
    const unsigned short* Ag1 = A + (size_t)(m0 + row1) * K + ke1;
    const unsigned short* Bg0 = B + (size_t)(n0 + row0) * K + ke0;
    const unsigned short* Bg1 = B + (size_t)(n0 + row1) * K + ke1;

    const int rsel = lane & 15, ksel = (lane >> 4) * 8;

    for (int kk = 0; kk < K; kk += 32) {
        gload_lds16(Ag0 + kk, &As[si0]);
        gload_lds16(Ag1 + kk, &As[si1]);
        gload_lds16(Bg0 + kk, &Bs[si0]);
        gload_lds16(Bg1 + kk, &Bs[si1]);
        __syncthreads();                            // drains vmcnt before barrier
        bf16x8 af[4], bfv[4];
        #pragma unroll
        for (int m = 0; m < 4; ++m)
            af[m] = *(const bf16x8*)&As[(wr * 64 + m * 16 + rsel) * 32 + ksel];
        #pragma unroll
        for (int n = 0; n < 4; ++n)
            bfv[n] = *(const bf16x8*)&Bs[(wc * 64 + n * 16 + rsel) * 32 + ksel];
        #pragma unroll
        for (int m = 0; m < 4; ++m)
            #pragma unroll
            for (int n = 0; n < 4; ++n)
                acc[m][n] = __builtin_amdgcn_mfma_f32_16x16x32_bf16(af[m], bfv[n], acc[m][n], 0, 0, 0);
        __syncthreads();                            // LDS reads done before next stage
    }

    // C/D layout: col = lane&15, row = (lane>>4)*4 + j   [m89/m91 verified]
    const int cn = lane & 15, rbase = (lane >> 4) * 4;
    #pragma unroll
    for (int n = 0; n < 4; ++n) {
        int gn = n0 + wc * 64 + n * 16 + cn;
        float bv = bias ? bias[gn] : 0.f;
        #pragma unroll
        for (int m = 0; m < 4; ++m) {
            #pragma unroll
            for (int j = 0; j < 4; ++j) {
                int gm = m0 + wr * 64 + m * 16 + rbase + j;
                float v = acc[m][n][j] + bv;
                if (act == 1) v = v / (1.f + __expf(-v));   // silu
                if (resid) v += resid[(size_t)gm * N + gn];
                C[(size_t)gm * N + gn] = v;
            }
        }
    }
}

// ---------------- generic fp32 GEMM (small shapes only) ----------------
#define BM 64
#define BN 64
#define BK 16
__global__ __launch_bounds__(256) void gemm_fp32(
    const float* __restrict__ A, const float* __restrict__ W,
    const float* __restrict__ bias, const float* __restrict__ resid,
    float* __restrict__ C, int M, int N, int K, int act) {
    __shared__ float As[BK][BM + 1];
    __shared__ float Ws[BK][BN + 1];
    int tid = threadIdx.x;
    int tx = tid & 15, ty = tid >> 4;
    int m0 = blockIdx.y * BM, n0 = blockIdx.x * BN;
    float acc[4][4] = {};
    for (int k0 = 0; k0 < K; k0 += BK) {
        int r  = tid >> 2;
        int c4 = (tid & 3) * 4;
        const float4 av = *(const float4*)(A + (size_t)(m0 + r) * K + k0 + c4);
        As[c4 + 0][r] = av.x; As[c4 + 1][r] = av.y;
        As[c4 + 2][r] = av.z; As[c4 + 3][r] = av.w;
        int n = n0 + r;
        float4 wv = make_float4(0.f, 0.f, 0.f, 0.f);
        if (n < N) wv = *(const float4*)(W + (size_t)n * K + k0 + c4);
        Ws[c4 + 0][r] = wv.x; Ws[c4 + 1][r] = wv.y;
        Ws[c4 + 2][r] = wv.z; Ws[c4 + 3][r] = wv.w;
        __syncthreads();
        #pragma unroll
        for (int k = 0; k < BK; ++k) {
            float a[4], b[4];
            #pragma unroll
            for (int i = 0; i < 4; ++i) a[i] = As[k][ty + 16 * i];
            #pragma unroll
            for (int j = 0; j < 4; ++j) b[j] = Ws[k][tx + 16 * j];
            #pragma unroll
            for (int i = 0; i < 4; ++i)
                #pragma unroll
                for (int j = 0; j < 4; ++j) acc[i][j] += a[i] * b[j];
        }
        __syncthreads();
    }
    #pragma unroll
    for (int i = 0; i < 4; ++i) {
        int m = m0 + ty + 16 * i;
        #pragma unroll
        for (int j = 0; j < 4; ++j) {
            int n = n0 + tx + 16 * j;
            if (n >= N) continue;
            float v = acc[i][j];
            if (bias) v += bias[n];
            if (act == 1)      v = v / (1.f + __expf(-v));
            else if (act == 2) v = (v > 20.f) ? v : log1pf(__expf(v));
            if (resid) v += resid[(size_t)m * N + n];
            C[(size_t)m * N + n] = v;
        }
    }
}

// ---------------- selective-scan ----------------
// y = (sum_n s*C + u*D) * silu(res), y written as bf16 (feeds out-proj MFMA GEMM)
__global__ __launch_bounds__(256) void scan_k(
    const float* __restrict__ delta, const float* __restrict__ u,
    const float* __restrict__ Bm, const float* __restrict__ Cm,
    const float* __restrict__ A_log, const float* __restrict__ Dp,
    const float* __restrict__ res, unsigned short* __restrict__ y) {
    int tid = blockIdx.x * 256 + threadIdx.x;
    int d = tid >> 4, n = tid & 15;
    float A  = -__expf(A_log[d * D_STATE + n]);
    float Dd = Dp[d];
    float s = 0.f;
    for (int t = 0; t < SEQLEN; ++t) {
        float dlt = delta[(size_t)t * D_IN + d];
        float ut  = u[(size_t)t * D_IN + d];
        float Bt  = Bm[t * D_STATE + n];
        float Ct  = Cm[t * D_STATE + n];
        s = __expf(dlt * A) * s + dlt * ut * Bt;
        float p = s * Ct;
        p += __shfl_xor(p, 1);
        p += __shfl_xor(p, 2);
        p += __shfl_xor(p, 4);
        p += __shfl_xor(p, 8);
        if (n == 0) {
            float r = res[(size_t)t * D_IN + d];
            y[(size_t)t * D_IN + d] = f2bf((p + ut * Dd) * (r / (1.f + __expf(-r))));
        }
    }
}

// ---------------- host side ----------------
static inline void launch_gemm_bf16(const unsigned short* A, const unsigned short* B,
                                    const float* bias, const float* resid, float* C,
                                    int M, int N, int K, int act, hipStream_t stream) {
    dim3 grid(N / 128, M / 128);
    gemm_bf16<<<grid, 256, 0, stream>>>(A, B, bias, resid, C, M, N, K, act);
}
static inline void launch_gemm_f32(const float* A, const float* W, const float* bias,
                                   const float* resid, float* C,
                                   int M, int N, int K, int act, hipStream_t stream) {
    dim3 grid((N + BN - 1) / BN, (M + BM - 1) / BM);
    gemm_fp32<<<grid, 256, 0, stream>>>(A, W, bias, resid, C, M, N, K, act);
}
static inline void launch_cast(const float* in, unsigned short* out, int n, hipStream_t stream) {
    cast_f32_bf16<<<(n / 8 + 255) / 256, 256, 0, stream>>>(in, out, n);
}

extern "C" void kernel_launch(void* const* d_in, const int* in_sizes, int n_in,
                              void* d_out, int out_size, void* d_ws, size_t ws_size,
                              hipStream_t stream) {
    const int*   ids      = (const int*)d_in[0];
    const float* emb      = (const float*)d_in[1];
    const float* W_res    = (const float*)d_in[2];
    const float* b_res    = (const float*)d_in[3];
    const float* W_state  = (const float*)d_in[4];
    const float* b_state  = (const float*)d_in[5];
    const float* W_conv   = (const float*)d_in[6];
    const float* W_dt     = (const float*)d_in[7];
    const float* b_dt     = (const float*)d_in[8];
    const float* W_B      = (const float*)d_in[9];
    const float* b_B      = (const float*)d_in[10];
    const float* W_C      = (const float*)d_in[11];
    const float* b_C      = (const float*)d_in[12];
    const float* W_dtp    = (const float*)d_in[13];
    const float* b_dtp    = (const float*)d_in[14];
    const float* A_log    = (const float*)d_in[15];
    const float* D_param  = (const float*)d_in[16];
    const float* W_out    = (const float*)d_in[17];
    const float* b_out    = (const float*)d_in[18];
    const float* norm_w   = (const float*)d_in[19];
    const float* fnorm_w  = (const float*)d_in[20];
    float* out = (float*)d_out;

    // ---- workspace carve-up ----
    float* p = (float*)d_ws;
    float* e     = p; p += SEQLEN * D_MODEL;
    float* resb  = p; p += SEQLEN * D_IN;
    float* x     = p; p += SEQLEN * D_IN;
    float* u     = p; p += SEQLEN * D_IN;
    float* dtl   = p; p += SEQLEN * DT_RANK;
    float* delta = p; p += SEQLEN * D_IN;
    float* Bm    = p; p += SEQLEN * D_STATE;
    float* Cm    = p; p += SEQLEN * D_STATE;
    unsigned short* q = (unsigned short*)p;
    unsigned short* xn_bf    = q; q += SEQLEN * D_MODEL;
    unsigned short* xcat_bf  = q; q += SEQLEN * KCAT;
    unsigned short* y_bf     = q; q += SEQLEN * D_IN;
    unsigned short* emb_bf   = q; q += VOCAB * D_MODEL;
    unsigned short* Wres_bf  = q; q += D_IN * D_MODEL;
    unsigned short* Wst_bf   = q; q += D_IN * D_MODEL;
    unsigned short* Wconv_bf = q; q += D_IN * KCAT;
    unsigned short* Wout_bf  = q; q += D_MODEL * D_IN;
    (void)ws_size; (void)in_sizes; (void)n_in; (void)out_size;

    launch_cast(emb, emb_bf, VOCAB * D_MODEL, stream);
    embed_gather<<<SEQLEN, 256, 0, stream>>>(ids, emb, e);

    for (int i = 0; i < N_LAYERS; ++i) {
        const float* Wres_i  = W_res   + (size_t)i * D_IN * D_MODEL;
        const float* bres_i  = b_res   + (size_t)i * D_IN;
        const float* Wst_i   = W_state + (size_t)i * D_IN * D_MODEL;
        const float* bst_i   = b_state + (size_t)i * D_IN;
        const float* Wcv_i   = W_conv  + (size_t)i * D_IN * KCAT;
        const float* Wdt_i   = W_dt    + (size_t)i * DT_RANK * D_IN;
        const float* bdt_i   = b_dt    + (size_t)i * DT_RANK;
        const float* WB_i    = W_B     + (size_t)i * D_STATE * D_IN;
        const float* bB_i    = b_B     + (size_t)i * D_STATE;
        const float* WC_i    = W_C     + (size_t)i * D_STATE * D_IN;
        const float* bC_i    = b_C     + (size_t)i * D_STATE;
        const float* Wdtp_i  = W_dtp   + (size_t)i * D_IN * DT_RANK;
        const float* bdtp_i  = b_dtp   + (size_t)i * D_IN;
        const float* Alog_i  = A_log   + (size_t)i * D_IN * D_STATE;
        const float* Dp_i    = D_param + (size_t)i * D_IN;
        const float* Wout_i  = W_out   + (size_t)i * D_MODEL * D_IN;
        const float* bout_i  = b_out   + (size_t)i * D_MODEL;
        const float* nw_i    = norm_w  + (size_t)i * D_MODEL;

        // weight casts for this layer
        launch_cast(Wres_i, Wres_bf, D_IN * D_MODEL, stream);
        launch_cast(Wst_i,  Wst_bf,  D_IN * D_MODEL, stream);
        launch_cast(Wcv_i,  Wconv_bf, D_IN * KCAT, stream);
        launch_cast(Wout_i, Wout_bf, D_MODEL * D_IN, stream);

        rmsnorm_k<<<SEQLEN, 256, 0, stream>>>(e, nw_i, xn_bf, D_MODEL);
        launch_gemm_bf16(xn_bf, Wres_bf, bres_i, nullptr, resb, SEQLEN, D_IN, D_MODEL, 0, stream);
        launch_gemm_bf16(xn_bf, Wst_bf,  bst_i,  nullptr, x,    SEQLEN, D_IN, D_MODEL, 0, stream);
        build_xcat<<<(SEQLEN * D_IN + 255) / 256, 256, 0, stream>>>(x, xcat_bf);
        launch_gemm_bf16(xcat_bf, Wconv_bf, nullptr, nullptr, u, SEQLEN, D_IN, KCAT, 1, stream);
        launch_gemm_f32(u, Wdt_i, bdt_i, nullptr, dtl, SEQLEN, DT_RANK, D_IN, 0, stream);
        launch_gemm_f32(dtl, Wdtp_i, bdtp_i, nullptr, delta, SEQLEN, D_IN, DT_RANK, 2, stream);
        launch_gemm_f32(u, WB_i, bB_i, nullptr, Bm, SEQLEN, D_STATE, D_IN, 0, stream);
        launch_gemm_f32(u, WC_i, bC_i, nullptr, Cm, SEQLEN, D_STATE, D_IN, 0, stream);
        scan_k<<<(D_IN * D_STATE) / 256, 256, 0, stream>>>(delta, u, Bm, Cm,
                                                           Alog_i, Dp_i, resb, y_bf);
        launch_gemm_bf16(y_bf, Wout_bf, bout_i, e, e, SEQLEN, D_MODEL, D_IN, 0, stream);
    }

    rmsnorm_k<<<SEQLEN, 256, 0, stream>>>(e, fnorm_w, xn_bf, D_MODEL);
    launch_gemm_bf16(xn_bf, emb_bf, nullptr, nullptr, out, SEQLEN, VOCAB, D_MODEL, 0, stream);
}

// Round 4
// 1072.808 us; speedup vs baseline: 4.8991x; 2.9560x over previous
//
#include <hip/hip_runtime.h>
#include <hip/hip_bf16.h>
#include <math.h>
#include <stdint.h>

// ---------------- problem constants ----------------
#define SEQLEN   1024
#define D_MODEL  768
#define D_IN     1536
#define D_STATE  16
#define D_CONV   4
#define DT_RANK  48
#define VOCAB    32000
#define N_LAYERS 2
#define KCAT     (D_IN * D_CONV)   // 6144

// scan chunking
#define CL      16                 // chunk length
#define NCHUNK  (SEQLEN / CL)      // 64
#define DBLK    (D_IN / 256)       // 6 blocks per chunk

// fused skinny GEMM (dt|B|C): N=80 = 48+16+16
#define NSM 80
#define KSPL 6
#define KCH (D_IN / KSPL)          // 256

using bf16x8 = __attribute__((ext_vector_type(8))) short;
using f32x4  = __attribute__((ext_vector_type(4))) float;

__device__ __forceinline__ unsigned short f2bf(float f) {
    unsigned u = __builtin_bit_cast(unsigned, f);
    unsigned r = u + 0x7FFFu + ((u >> 16) & 1u);   // round-to-nearest-even
    return (unsigned short)(r >> 16);
}

// async global->LDS, 16 bytes per lane (C-style casts => addrspacecast)
__device__ __forceinline__ void gload_lds16(const unsigned short* g, unsigned short* l) {
    auto* lds = (__attribute__((address_space(3))) unsigned int*)(l);
    auto* gp  = (const __attribute__((address_space(1))) unsigned int*)(g);
    __builtin_amdgcn_global_load_lds(gp, lds, 16, 0, 0);
}

// ---------------- fp32 -> bf16 cast ----------------
__global__ __launch_bounds__(256) void cast_f32_bf16(const float* __restrict__ in,
                                                     unsigned short* __restrict__ out, int n) {
    int i = (blockIdx.x * 256 + threadIdx.x) * 8;
    if (i >= n) return;
    float4 a = *(const float4*)(in + i);
    float4 b = *(const float4*)(in + i + 4);
    uint4 v;
    v.x = f2bf(a.x) | ((unsigned)f2bf(a.y) << 16);
    v.y = f2bf(a.z) | ((unsigned)f2bf(a.w) << 16);
    v.z = f2bf(b.x) | ((unsigned)f2bf(b.y) << 16);
    v.w = f2bf(b.z) | ((unsigned)f2bf(b.w) << 16);
    *(uint4*)(out + i) = v;
}

// ---------------- embedding gather (fp32) ----------------
__global__ void embed_gather(const int* __restrict__ ids,
                             const float* __restrict__ emb,
                             float* __restrict__ e) {
    int t = blockIdx.x;
    int id = ids[t];
    const float* src = emb + (size_t)id * D_MODEL;
    float* dst = e + (size_t)t * D_MODEL;
    for (int c = threadIdx.x; c < D_MODEL; c += blockDim.x) dst[c] = src[c];
}

// ---------------- rmsnorm: fp32 in, bf16 out ----------------
__global__ __launch_bounds__(256) void rmsnorm_k(const float* __restrict__ in,
                                                 const float* __restrict__ w,
                                                 unsigned short* __restrict__ out,
                                                 int cols) {
    int row = blockIdx.x;
    const float* x = in + (size_t)row * cols;
    float ss = 0.f;
    for (int c = threadIdx.x; c < cols; c += 256) { float v = x[c]; ss += v * v; }
    #pragma unroll
    for (int off = 32; off > 0; off >>= 1) ss += __shfl_down(ss, off);
    __shared__ float red[4];
    int lane = threadIdx.x & 63, wv = threadIdx.x >> 6;
    if (lane == 0) red[wv] = ss;
    __syncthreads();
    float tot = red[0] + red[1] + red[2] + red[3];
    float scale = rsqrtf(tot / (float)cols + 1e-5f);
    for (int c = threadIdx.x; c < cols; c += 256)
        out[(size_t)row * cols + c] = f2bf(x[c] * scale * w[c]);
}

// ---------------- build Xcat (bf16 out) ----------------
__global__ void build_xcat(const float* __restrict__ x, unsigned short* __restrict__ xc) {
    int idx = blockIdx.x * blockDim.x + threadIdx.x;  // t*D_IN + i
    if (idx >= SEQLEN * D_IN) return;
    int t = idx / D_IN, i = idx - t * D_IN;
    unsigned short h0 = (t >= 3) ? f2bf(x[(size_t)(t - 3) * D_IN + i]) : 0;
    unsigned short h1 = (t >= 2) ? f2bf(x[(size_t)(t - 2) * D_IN + i]) : 0;
    unsigned short h2 = (t >= 1) ? f2bf(x[(size_t)(t - 1) * D_IN + i]) : 0;
    unsigned short h3 = f2bf(x[(size_t)t * D_IN + i]);
    uint2 v;
    v.x = h0 | ((unsigned)h1 << 16);
    v.y = h2 | ((unsigned)h3 << 16);
    *(uint2*)(xc + (size_t)idx * 4) = v;
}

// ---------------- bf16 MFMA GEMM (128x128 tile, BK=32, 4 waves) ----------------
__global__ __launch_bounds__(256) void gemm_bf16(
    const unsigned short* __restrict__ A, const unsigned short* __restrict__ B,
    const float* __restrict__ bias, const float* __restrict__ resid,
    float* __restrict__ C, int M, int N, int K, int act) {
    __shared__ unsigned short As[128 * 32];
    __shared__ unsigned short Bs[128 * 32];
    const int tid = threadIdx.x;
    const int wid = tid >> 6, lane = tid & 63;
    const int wr = wid >> 1, wc = wid & 1;
    const int m0 = blockIdx.y * 128, n0 = blockIdx.x * 128;

    f32x4 acc[4][4] = {};

    const int si0 = tid * 8;
    const int si1 = (tid + 256) * 8;
    const int row0 = si0 >> 5, ke0 = si0 & 31;
    const int row1 = si1 >> 5, ke1 = si1 & 31;
    const unsigned short* Ag0 = A + (size_t)(m0 + row0) * K + ke0;
    const unsigned short* Ag1 = A + (size_t)(m0 + row1) * K + ke1;
    const unsigned short* Bg0 = B + (size_t)(n0 + row0) * K + ke0;
    const unsigned short* Bg1 = B + (size_t)(n0 + row1) * K + ke1;

    const int rsel = lane & 15, ksel = (lane >> 4) * 8;

    for (int kk = 0; kk < K; kk += 32) {
        gload_lds16(Ag0 + kk, &As[si0]);
        gload_lds16(Ag1 + kk, &As[si1]);
        gload_lds16(Bg0 + kk, &Bs[si0]);
        gload_lds16(Bg1 + kk, &Bs[si1]);
        __syncthreads();
        bf16x8 af[4], bfv[4];
        #pragma unroll
        for (int m = 0; m < 4; ++m)
            af[m] = *(const bf16x8*)&As[(wr * 64 + m * 16 + rsel) * 32 + ksel];
        #pragma unroll
        for (int n = 0; n < 4; ++n)
            bfv[n] = *(const bf16x8*)&Bs[(wc * 64 + n * 16 + rsel) * 32 + ksel];
        #pragma unroll
        for (int m = 0; m < 4; ++m)
            #pragma unroll
            for (int n = 0; n < 4; ++n)
                acc[m][n] = __builtin_amdgcn_mfma_f32_16x16x32_bf16(af[m], bfv[n], acc[m][n], 0, 0, 0);
        __syncthreads();
    }

    const int cn = lane & 15, rbase = (lane >> 4) * 4;
    #pragma unroll
    for (int n = 0; n < 4; ++n) {
        int gn = n0 + wc * 64 + n * 16 + cn;
        float bv = bias ? bias[gn] : 0.f;
        #pragma unroll
        for (int m = 0; m < 4; ++m) {
            #pragma unroll
            for (int j = 0; j < 4; ++j) {
                int gm = m0 + wr * 64 + m * 16 + rbase + j;
                float v = acc[m][n][j] + bv;
                if (act == 1) v = v / (1.f + __expf(-v));   // silu
                if (resid) v += resid[(size_t)gm * N + gn];
                C[(size_t)gm * N + gn] = v;
            }
        }
    }
}

// ---------------- generic fp32 GEMM with strides (dtp GEMM only) ----------------
#define BM 64
#define BN 64
#define BK 16
__global__ __launch_bounds__(256) void gemm_fp32(
    const float* __restrict__ A, const float* __restrict__ W,
    const float* __restrict__ bias, float* __restrict__ C,
    int M, int N, int K, int lda, int ldw, int ldc, int act) {
    __shared__ float As[BK][BM + 1];
    __shared__ float Ws[BK][BN + 1];
    int tid = threadIdx.x;
    int tx = tid & 15, ty = tid >> 4;
    int m0 = blockIdx.y * BM, n0 = blockIdx.x * BN;
    float acc[4][4] = {};
    for (int k0 = 0; k0 < K; k0 += BK) {
        int r  = tid >> 2;
        int c4 = (tid & 3) * 4;
        const float4 av = *(const float4*)(A + (size_t)(m0 + r) * lda + k0 + c4);
        As[c4 + 0][r] = av.x; As[c4 + 1][r] = av.y;
        As[c4 + 2][r] = av.z; As[c4 + 3][r] = av.w;
        int n = n0 + r;
        float4 wv = make_float4(0.f, 0.f, 0.f, 0.f);
        if (n < N) wv = *(const float4*)(W + (size_t)n * ldw + k0 + c4);
        Ws[c4 + 0][r] = wv.x; Ws[c4 + 1][r] = wv.y;
        Ws[c4 + 2][r] = wv.z; Ws[c4 + 3][r] = wv.w;
        __syncthreads();
        #pragma unroll
        for (int k = 0; k < BK; ++k) {
            float a[4], b[4];
            #pragma unroll
            for (int i = 0; i < 4; ++i) a[i] = As[k][ty + 16 * i];
            #pragma unroll
            for (int j = 0; j < 4; ++j) b[j] = Ws[k][tx + 16 * j];
            #pragma unroll
            for (int i = 0; i < 4; ++i)
                #pragma unroll
                for (int j = 0; j < 4; ++j) acc[i][j] += a[i] * b[j];
        }
        __syncthreads();
    }
    #pragma unroll
    for (int i = 0; i < 4; ++i) {
        int m = m0 + ty + 16 * i;
        #pragma unroll
        for (int j = 0; j < 4; ++j) {
            int n = n0 + tx + 16 * j;
            if (n >= N) continue;
            float v = acc[i][j];
            if (bias) v += bias[n];
            if (act == 1)      v = v / (1.f + __expf(-v));
            else if (act == 2) v = (v > 20.f) ? v : log1pf(__expf(v));
            C[(size_t)m * ldc + n] = v;
        }
    }
}

// ---------------- pack W_dt|W_B|W_C -> Wsm[80][1536], biases -> bsm[80] ----------------
__global__ __launch_bounds__(256) void pack_wsm(
    const float* __restrict__ Wdt, const float* __restrict__ WB, const float* __restrict__ WC,
    const float* __restrict__ bdt, const float* __restrict__ bB, const float* __restrict__ bC,
    float* __restrict__ Wsm, float* __restrict__ bsm) {
    int idx = blockIdx.x * 256 + threadIdx.x;
    if (idx < NSM * D_IN / 4) {
        int row = idx / (D_IN / 4), c4 = (idx % (D_IN / 4)) * 4;
        const float* src = (row < 48) ? Wdt + (size_t)row * D_IN + c4
                         : (row < 64) ? WB + (size_t)(row - 48) * D_IN + c4
                                      : WC + (size_t)(row - 64) * D_IN + c4;
        *(float4*)(Wsm + (size_t)row * D_IN + c4) = *(const float4*)src;
    }
    if (idx < NSM)
        bsm[idx] = (idx < 48) ? bdt[idx] : (idx < 64) ? bB[idx - 48] : bC[idx - 64];
}

// ---------------- fused skinny fp32 GEMM: part[ks][M][80] = u @ Wsm^T (K-split) ----------------
__global__ __launch_bounds__(256) void gemm_f32_skinny(
    const float* __restrict__ A,   // [1024][1536]
    const float* __restrict__ W,   // [80][1536]
    float* __restrict__ part) {    // [KSPL][1024][80]
    __shared__ float As[16][64 + 1];
    __shared__ float Ws[16][NSM + 1];
    const int m0 = blockIdx.x * 64;
    const int ks = blockIdx.y;
    const int tid = threadIdx.x;
    const int tx = tid & 15, ty = tid >> 4;
    float acc[4][5] = {};
    for (int k0 = ks * KCH; k0 < (ks + 1) * KCH; k0 += 16) {
        {
            int r = tid >> 2, c4 = (tid & 3) * 4;
            float4 av = *(const float4*)(A + (size_t)(m0 + r) * D_IN + k0 + c4);
            As[c4 + 0][r] = av.x; As[c4 + 1][r] = av.y;
            As[c4 + 2][r] = av.z; As[c4 + 3][r] = av.w;
            float4 wv = *(const float4*)(W + (size_t)r * D_IN + k0 + c4);   // rows 0..63
            Ws[c4 + 0][r] = wv.x; Ws[c4 + 1][r] = wv.y;
            Ws[c4 + 2][r] = wv.z; Ws[c4 + 3][r] = wv.w;
            if (tid < 64) {                                                  // rows 64..79
                int r2 = 64 + (tid >> 2);
                float4 w2 = *(const float4*)(W + (size_t)r2 * D_IN + k0 + c4);
                Ws[c4 + 0][r2] = w2.x; Ws[c4 + 1][r2] = w2.y;
                Ws[c4 + 2][r2] = w2.z; Ws[c4 + 3][r2] = w2.w;
            }
        }
        __syncthreads();
        #pragma unroll
        for (int k = 0; k < 16; ++k) {
            float a[4], b[5];
            #pragma unroll
            for (int i = 0; i < 4; ++i) a[i] = As[k][ty + 16 * i];
            #pragma unroll
            for (int j = 0; j < 5; ++j) b[j] = Ws[k][tx + 16 * j];
            #pragma unroll
            for (int i = 0; i < 4; ++i)
                #pragma unroll
                for (int j = 0; j < 5; ++j) acc[i][j] += a[i] * b[j];
        }
        __syncthreads();
    }
    float* po = part + ((size_t)ks * SEQLEN + m0) * NSM;
    #pragma unroll
    for (int i = 0; i < 4; ++i)
        #pragma unroll
        for (int j = 0; j < 5; ++j)
            po[(size_t)(ty + 16 * i) * NSM + tx + 16 * j] = acc[i][j];
}

__global__ __launch_bounds__(256) void skinny_reduce(
    const float* __restrict__ part, const float* __restrict__ bias,
    float* __restrict__ outp) {
    int idx = blockIdx.x * 256 + threadIdx.x;     // m*80+n
    if (idx >= SEQLEN * NSM) return;
    int n = idx % NSM;
    float v = bias[n];
    #pragma unroll
    for (int s = 0; s < KSPL; ++s) v += part[(size_t)s * SEQLEN * NSM + idx];
    outp[idx] = v;
}

// ---------------- chunked parallel scan ----------------
// fused[t][80]: cols 48..63 = B[t][n], 64..79 = C[t][n]
__global__ __launch_bounds__(256) void scan_pass1(
    const float* __restrict__ delta, const float* __restrict__ u,
    const float* __restrict__ fused, const float* __restrict__ A_log,
    float* __restrict__ Aprod, float* __restrict__ Bacc) {
    const int c = blockIdx.x / DBLK;
    const int d = (blockIdx.x % DBLK) * 256 + threadIdx.x;
    const int t0 = c * CL;
    __shared__ float Bs[CL][D_STATE];
    {
        int tt = threadIdx.x >> 4, nn = threadIdx.x & 15;   // 256 = CL*16 exactly
        Bs[tt][nn] = fused[(size_t)(t0 + tt) * NSM + 48 + nn];
    }
    __syncthreads();
    float A[16];
    #pragma unroll
    for (int n = 0; n < 16; ++n) A[n] = -__expf(A_log[d * 16 + n]);
    float Ap[16], Bc[16];
    #pragma unroll
    for (int n = 0; n < 16; ++n) { Ap[n] = 1.f; Bc[n] = 0.f; }
    for (int tt = 0; tt < CL; ++tt) {
        int t = t0 + tt;
        float dlt = delta[(size_t)t * D_IN + d];
        float ut  = u[(size_t)t * D_IN + d];
        float du  = dlt * ut;
        #pragma unroll
        for (int n = 0; n < 16; ++n) {
            float dA = __expf(dlt * A[n]);
            Ap[n] *= dA;
            Bc[n] = dA * Bc[n] + du * Bs[tt][n];
        }
    }
    float* ap = Aprod + ((size_t)c * D_IN + d) * 16;
    float* bc = Bacc + ((size_t)c * D_IN + d) * 16;
    #pragma unroll
    for (int n = 0; n < 16; n += 4) {
        *(float4*)(ap + n) = make_float4(Ap[n], Ap[n+1], Ap[n+2], Ap[n+3]);
        *(float4*)(bc + n) = make_float4(Bc[n], Bc[n+1], Bc[n+2], Bc[n+3]);
    }
}

__global__ __launch_bounds__(256) void scan_pass2(
    const float* __restrict__ Aprod, const float* __restrict__ Bacc,
    float* __restrict__ Sin) {
    int idx = blockIdx.x * 256 + threadIdx.x;     // d*16+n, 24576 total
    float s = 0.f;
    for (int c = 0; c < NCHUNK; ++c) {
        size_t off = (size_t)c * D_IN * 16 + idx;
        Sin[off] = s;
        s = Aprod[off] * s + Bacc[off];
    }
}

__global__ __launch_bounds__(256) void scan_pass3(
    const float* __restrict__ delta, const float* __restrict__ u,
    const float* __restrict__ fused, const float* __restrict__ A_log,
    const float* __restrict__ Dp, const float* __restrict__ res,
    const float* __restrict__ Sin, unsigned short* __restrict__ y) {
    const int c = blockIdx.x / DBLK;
    const int d = (blockIdx.x % DBLK) * 256 + threadIdx.x;
    const int t0 = c * CL;
    __shared__ float Bs[CL][D_STATE];
    __shared__ float Cs[CL][D_STATE];
    {
        int tt = threadIdx.x >> 4, nn = threadIdx.x & 15;
        Bs[tt][nn] = fused[(size_t)(t0 + tt) * NSM + 48 + nn];
        Cs[tt][nn] = fused[(size_t)(t0 + tt) * NSM + 64 + nn];
    }
    __syncthreads();
    float A[16];
    #pragma unroll
    for (int n = 0; n < 16; ++n) A[n] = -__expf(A_log[d * 16 + n]);
    float s[16];
    const float* sin = Sin + ((size_t)c * D_IN + d) * 16;
    #pragma unroll
    for (int n = 0; n < 16; ++n) s[n] = sin[n];
    const float Dd = Dp[d];
    for (int tt = 0; tt < CL; ++tt) {
        int t = t0 + tt;
        float dlt = delta[(size_t)t * D_IN + d];
        float ut  = u[(size_t)t * D_IN + d];
        float du  = dlt * ut;
        float acc = 0.f;
        #pragma unroll
        for (int n = 0; n < 16; ++n) {
            float dA = __expf(dlt * A[n]);
            s[n] = dA * s[n] + du * Bs[tt][n];
            acc += s[n] * Cs[tt][n];
        }
        float r = res[(size_t)t * D_IN + d];
        y[(size_t)t * D_IN + d] = f2bf((acc + ut * Dd) * (r / (1.f + __expf(-r))));
    }
}

// ---------------- host side ----------------
static inline void launch_gemm_bf16(const unsigned short* A, const unsigned short* B,
                                    const float* bias, const float* resid, float* C,
                                    int M, int N, int K, int act, hipStream_t stream) {
    dim3 grid(N / 128, M / 128);
    gemm_bf16<<<grid, 256, 0, stream>>>(A, B, bias, resid, C, M, N, K, act);
}
static inline void launch_cast(const float* in, unsigned short* out, int n, hipStream_t stream) {
    cast_f32_bf16<<<(n / 8 + 255) / 256, 256, 0, stream>>>(in, out, n);
}

extern "C" void kernel_launch(void* const* d_in, const int* in_sizes, int n_in,
                              void* d_out, int out_size, void* d_ws, size_t ws_size,
                              hipStream_t stream) {
    const int*   ids      = (const int*)d_in[0];
    const float* emb      = (const float*)d_in[1];
    const float* W_res    = (const float*)d_in[2];
    const float* b_res    = (const float*)d_in[3];
    const float* W_state  = (const float*)d_in[4];
    const float* b_state  = (const float*)d_in[5];
    const float* W_conv   = (const float*)d_in[6];
    const float* W_dt     = (const float*)d_in[7];
    const float* b_dt     = (const float*)d_in[8];
    const float* W_B      = (const float*)d_in[9];
    const float* b_B      = (const float*)d_in[10];
    const float* W_C      = (const float*)d_in[11];
    const float* b_C      = (const float*)d_in[12];
    const float* W_dtp    = (const float*)d_in[13];
    const float* b_dtp    = (const float*)d_in[14];
    const float* A_log    = (const float*)d_in[15];
    const float* D_param  = (const float*)d_in[16];
    const float* W_out    = (const float*)d_in[17];
    const float* b_out    = (const float*)d_in[18];
    const float* norm_w   = (const float*)d_in[19];
    const float* fnorm_w  = (const float*)d_in[20];
    float* out = (float*)d_out;

    // ---- workspace carve-up ----
    float* p = (float*)d_ws;
    float* e     = p; p += SEQLEN * D_MODEL;
    float* resb  = p; p += SEQLEN * D_IN;
    float* x     = p; p += SEQLEN * D_IN;
    float* u     = p; p += SEQLEN * D_IN;
    float* delta = p; p += SEQLEN * D_IN;
    float* fused = p; p += SEQLEN * NSM;
    float* part  = p; p += KSPL * SEQLEN * NSM;
    float* Wsm   = p; p += NSM * D_IN;
    float* bsm   = p; p += NSM;
    float* Aprod = p; p += NCHUNK * D_IN * 16;
    float* Bacc  = p; p += NCHUNK * D_IN * 16;
    float* Sin   = p; p += NCHUNK * D_IN * 16;
    unsigned short* q = (unsigned short*)p;
    unsigned short* xn_bf    = q; q += SEQLEN * D_MODEL;
    unsigned short* xcat_bf  = q; q += SEQLEN * KCAT;
    unsigned short* y_bf     = q; q += SEQLEN * D_IN;
    unsigned short* emb_bf   = q; q += VOCAB * D_MODEL;
    unsigned short* Wres_bf  = q; q += D_IN * D_MODEL;
    unsigned short* Wst_bf   = q; q += D_IN * D_MODEL;
    unsigned short* Wconv_bf = q; q += D_IN * KCAT;
    unsigned short* Wout_bf  = q; q += D_MODEL * D_IN;
    (void)ws_size; (void)in_sizes; (void)n_in; (void)out_size;

    launch_cast(emb, emb_bf, VOCAB * D_MODEL, stream);
    embed_gather<<<SEQLEN, 256, 0, stream>>>(ids, emb, e);

    for (int i = 0; i < N_LAYERS; ++i) {
        const float* Wres_i  = W_res   + (size_t)i * D_IN * D_MODEL;
        const float* bres_i  = b_res   + (size_t)i * D_IN;
        const float* Wst_i   = W_state + (size_t)i * D_IN * D_MODEL;
        const float* bst_i   = b_state + (size_t)i * D_IN;
        const float* Wcv_i   = W_conv  + (size_t)i * D_IN * KCAT;
        const float* Wdt_i   = W_dt    + (size_t)i * DT_RANK * D_IN;
        const float* bdt_i   = b_dt    + (size_t)i * DT_RANK;
        const float* WB_i    = W_B     + (size_t)i * D_STATE * D_IN;
        const float* bB_i    = b_B     + (size_t)i * D_STATE;
        const float* WC_i    = W_C     + (size_t)i * D_STATE * D_IN;
        const float* bC_i    = b_C     + (size_t)i * D_STATE;
        const float* Wdtp_i  = W_dtp   + (size_t)i * D_IN * DT_RANK;
        const float* bdtp_i  = b_dtp   + (size_t)i * D_IN;
        const float* Alog_i  = A_log   + (size_t)i * D_IN * D_STATE;
        const float* Dp_i    = D_param + (size_t)i * D_IN;
        const float* Wout_i  = W_out   + (size_t)i * D_MODEL * D_IN;
        const float* bout_i  = b_out   + (size_t)i * D_MODEL;
        const float* nw_i    = norm_w  + (size_t)i * D_MODEL;

        launch_cast(Wres_i, Wres_bf, D_IN * D_MODEL, stream);
        launch_cast(Wst_i,  Wst_bf,  D_IN * D_MODEL, stream);
        launch_cast(Wcv_i,  Wconv_bf, D_IN * KCAT, stream);
        launch_cast(Wout_i, Wout_bf, D_MODEL * D_IN, stream);
        pack_wsm<<<(NSM * D_IN / 4 + 255) / 256, 256, 0, stream>>>(
            Wdt_i, WB_i, WC_i, bdt_i, bB_i, bC_i, Wsm, bsm);

        rmsnorm_k<<<SEQLEN, 256, 0, stream>>>(e, nw_i, xn_bf, D_MODEL);
        launch_gemm_bf16(xn_bf, Wres_bf, bres_i, nullptr, resb, SEQLEN, D_IN, D_MODEL, 0, stream);
        launch_gemm_bf16(xn_bf, Wst_bf,  bst_i,  nullptr, x,    SEQLEN, D_IN, D_MODEL, 0, stream);
        build_xcat<<<(SEQLEN * D_IN + 255) / 256, 256, 0, stream>>>(x, xcat_bf);
        launch_gemm_bf16(xcat_bf, Wconv_bf, nullptr, nullptr, u, SEQLEN, D_IN, KCAT, 1, stream);

        // fused dt|B|C projection (fp32, K-split) -> fused[1024][80]
        gemm_f32_skinny<<<dim3(SEQLEN / 64, KSPL), 256, 0, stream>>>(u, Wsm, part);
        skinny_reduce<<<(SEQLEN * NSM + 255) / 256, 256, 0, stream>>>(part, bsm, fused);

        // delta = softplus(fused[:, :48] @ W_dtp^T + b_dtp)
        gemm_fp32<<<dim3(D_IN / BN, SEQLEN / BM), 256, 0, stream>>>(
            fused, Wdtp_i, bdtp_i, delta, SEQLEN, D_IN, DT_RANK, NSM, DT_RANK, D_IN, 2);

        // chunked scan
        scan_pass1<<<NCHUNK * DBLK, 256, 0, stream>>>(delta, u, fused, Alog_i, Aprod, Bacc);
        scan_pass2<<<(D_IN * 16) / 256, 256, 0, stream>>>(Aprod, Bacc, Sin);
        scan_pass3<<<NCHUNK * DBLK, 256, 0, stream>>>(delta, u, fused, Alog_i,
                                                      Dp_i, resb, Sin, y_bf);

        launch_gemm_bf16(y_bf, Wout_bf, bout_i, e, e, SEQLEN, D_MODEL, D_IN, 0, stream);
    }

    rmsnorm_k<<<SEQLEN, 256, 0, stream>>>(e, fnorm_w, xn_bf, D_MODEL);
    launch_gemm_bf16(xn_bf, emb_bf, nullptr, nullptr, out, SEQLEN, VOCAB, D_MODEL, 0, stream);
}